// Round 6
// baseline (208.909 us; speedup 1.0000x reference)
//
#include <hip/hip_runtime.h>

// B=2, S=2048, E=1024, H=16, D=64
#define SEQ 2048
#define EMB 1024
#define KDIM 1024
#define CF 0.180336880111113f  // (1/sqrt(64)) * log2(e), folded into Q

typedef __attribute__((ext_vector_type(8))) short short8_t;
typedef __attribute__((ext_vector_type(4))) float floatx4;
typedef __attribute__((ext_vector_type(4))) unsigned short ushort4_t;

#define GLOAD16(gp, lp)                                                        \
  __builtin_amdgcn_global_load_lds(                                            \
      (const __attribute__((address_space(1))) void*)(gp),                     \
      (__attribute__((address_space(3))) void*)(lp), 16, 0, 0)

#define WGBAR()                                   \
  do {                                            \
    __asm__ __volatile__("" ::: "memory");        \
    __builtin_amdgcn_s_barrier();                 \
    __asm__ __volatile__("" ::: "memory");        \
  } while (0)

static __device__ __forceinline__ unsigned short f2bf(float x) {
  unsigned int u = __float_as_uint(x);
  return (unsigned short)((u + 0x7fffu + ((u >> 16) & 1u)) >> 16);
}
static __device__ __forceinline__ float bf2f(unsigned short h) {
  return __uint_as_float(((unsigned int)h) << 16);
}

// ---------------------------------------------------------------------------
// fp32 -> bf16 elementwise
// ---------------------------------------------------------------------------
__global__ __launch_bounds__(256) void conv_bf(
    const float* __restrict__ X, unsigned short* __restrict__ Y, int n4) {
  int i = blockIdx.x * 256 + threadIdx.x;
  if (i >= n4) return;
  float4 v = *(const float4*)&X[(size_t)i * 4];
  ushort4_t h = {f2bf(v.x), f2bf(v.y), f2bf(v.z), f2bf(v.w)};
  *(ushort4_t*)&Y[(size_t)i * 4] = h;
}

// ---------------------------------------------------------------------------
// W[K,N] fp32 -> Wt[N,K] bf16 (64x64 LDS tile transpose + convert)
// ---------------------------------------------------------------------------
__global__ __launch_bounds__(256) void tconv(
    const float* __restrict__ W, unsigned short* __restrict__ T, int N, int K) {
  __shared__ float Tl[64][65];
  const int tid = threadIdx.x, lx = tid & 15, ly = tid >> 4;
  const int n0 = blockIdx.x * 64, k0 = blockIdx.y * 64;
#pragma unroll
  for (int u = 0; u < 4; ++u) {
    int r = u * 16 + ly;
    float4 v = *(const float4*)&W[(size_t)(k0 + r) * N + n0 + lx * 4];
    Tl[r][lx * 4 + 0] = v.x;
    Tl[r][lx * 4 + 1] = v.y;
    Tl[r][lx * 4 + 2] = v.z;
    Tl[r][lx * 4 + 3] = v.w;
  }
  __syncthreads();
#pragma unroll
  for (int u = 0; u < 4; ++u) {
    int n = u * 16 + ly;
    ushort4_t h;
#pragma unroll
    for (int v = 0; v < 4; ++v) h[v] = f2bf(Tl[lx * 4 + v][n]);
    *(ushort4_t*)&T[(size_t)(n0 + n) * K + k0 + lx * 4] = h;
  }
}

// ---------------------------------------------------------------------------
// Plain bf16 MFMA GEMM, BK=64: C = A @ Bt^T + bias.  Tile 128 x BN.
//   A: [M,1024] bf16 row-major;  Bt: [N,1024] bf16 (W transposed)
// MODE 0 (TR, BN=128): qk bf16 out [B,S,2048], q cols (<1024) scaled by CF.
//                      Transposed acc: regs = 4 consecutive cols -> ushort4.
// MODE 1 (normal, BN=128): vt bf16 out [B,H,D,S] (regs = consecutive s rows).
// MODE 2 (TR, BN=64): fp32 out [M,1024], float4 stores.
// ---------------------------------------------------------------------------
template <int MODE, int BN>
__global__ __launch_bounds__(256) void gemm_bf(
    const unsigned short* __restrict__ Ag, const unsigned short* __restrict__ Bg,
    const float* __restrict__ bias, float* __restrict__ outF,
    unsigned short* __restrict__ qk, unsigned short* __restrict__ vt,
    int colbase) {
  __shared__ __attribute__((aligned(16))) unsigned short Ah[128 * 64];
  __shared__ __attribute__((aligned(16))) unsigned short Bh[BN * 64];
  const int NJ = BN / 32;  // j-frag groups per wave

  const int tid = threadIdx.x;
  const int w = tid >> 6, lane = tid & 63;
  const int quad = lane >> 4, c = lane & 15;
  const int bm = blockIdx.y * 128, bn = colbase + blockIdx.x * BN;
  const int wm = (w >> 1) * 64, wn = (w & 1) * (BN / 2);

  // staging: waves 0,1 -> A halves; waves 2,3 -> B halves
  const unsigned short* gsrc = (w < 2) ? Ag : Bg;
  unsigned short* ldst = (w < 2) ? (Ah + (w & 1) * 64 * 64) : (Bh + (w & 1) * (BN / 2) * 64);
  const int rbase = (w < 2) ? (bm + (w & 1) * 64) : (bn + (w & 1) * (BN / 2));
  const int nloads = (w < 2) ? 8 : (BN / 16);
  const int srow = lane >> 3;          // 0..7
  const int sblk = (lane & 7) ^ srow;  // XOR chunk swizzle (8x16B chunks/row)
  const char* gp0 = (const char*)(gsrc + (size_t)(rbase + srow) * KDIM) + sblk * 16;

  floatx4 acc[4][NJ];
  const floatx4 z = {0.f, 0.f, 0.f, 0.f};
#pragma unroll
  for (int i = 0; i < 4; ++i)
#pragma unroll
    for (int j = 0; j < NJ; ++j) acc[i][j] = z;

  const int rk = c & 7;  // read-side swizzle key (row&7 == c&7)

  for (int k0 = 0; k0 < KDIM; k0 += 64) {
    __syncthreads();
    const char* gp = gp0 + k0 * 2;
    for (int i = 0; i < nloads; ++i) GLOAD16(gp + (size_t)i * 8 * (KDIM * 2), &ldst[i * 512]);
    __syncthreads();

#pragma unroll
    for (int kq = 0; kq < 2; ++kq) {
      const int oct = ((4 * kq + quad) ^ rk) * 8;
      short8_t a[4], b[NJ];
#pragma unroll
      for (int i = 0; i < 4; ++i)
        a[i] = *(const short8_t*)&Ah[(wm + 16 * i + c) * 64 + oct];
#pragma unroll
      for (int j = 0; j < NJ; ++j)
        b[j] = *(const short8_t*)&Bh[(wn + 16 * j + c) * 64 + oct];
#pragma unroll
      for (int i = 0; i < 4; ++i)
#pragma unroll
        for (int j = 0; j < NJ; ++j) {
          if (MODE == 1)
            acc[i][j] = __builtin_amdgcn_mfma_f32_16x16x32_bf16(a[i], b[j], acc[i][j], 0, 0, 0);
          else  // transposed: lane = A-row (m), regs = 4 consecutive B-rows (n)
            acc[i][j] = __builtin_amdgcn_mfma_f32_16x16x32_bf16(b[j], a[i], acc[i][j], 0, 0, 0);
        }
    }
  }

  if (MODE == 1) {  // normal orientation: regs = 4 consecutive m rows
#pragma unroll
    for (int i = 0; i < 4; ++i) {
      const int r0 = bm + wm + 16 * i + quad * 4;
#pragma unroll
      for (int j = 0; j < NJ; ++j) {
        const int col = bn + wn + 16 * j + c;
        const float bv = bias[col];
        const int c2 = col - 2048, hh = c2 >> 6, d = c2 & 63;
        const int bb = r0 >> 11, s = r0 & 2047;
        ushort4_t pk = {f2bf(acc[i][j][0] + bv), f2bf(acc[i][j][1] + bv),
                        f2bf(acc[i][j][2] + bv), f2bf(acc[i][j][3] + bv)};
        *(ushort4_t*)&vt[((size_t)(bb * 16 + hh) * 64 + d) * 2048 + s] = pk;
      }
    }
  } else {  // transposed: lane = row m, regs = 4 consecutive cols
#pragma unroll
    for (int i = 0; i < 4; ++i) {
      const int row = bm + wm + 16 * i + c;
#pragma unroll
      for (int j = 0; j < NJ; ++j) {
        const int col0 = bn + wn + 16 * j + quad * 4;
        floatx4 v = acc[i][j] + *(const floatx4*)&bias[col0];
        if (MODE == 0) {
          if (col0 < 1024) v = v * CF;
          ushort4_t pk = {f2bf(v[0]), f2bf(v[1]), f2bf(v[2]), f2bf(v[3])};
          *(ushort4_t*)&qk[(size_t)row * 2048 + col0] = pk;
        } else {
          *(floatx4*)&outF[(size_t)row * 1024 + col0] = v;
        }
      }
    }
  }
}

// ---------------------------------------------------------------------------
// K/V staging for 8-wave attn blocks: waves 0-3 stage K rows w*16..+15,
// waves 4-7 stage V^T rows (w-4)*16..+15. 2 GLOAD16 per wave.
// ---------------------------------------------------------------------------
static __device__ __forceinline__ void stage_kv8(
    int w, int srow, int sblkg, const unsigned short* __restrict__ gK,
    const unsigned short* __restrict__ gV, unsigned short* Kbuf,
    unsigned short* Vbuf, int jt) {
  if (w < 4) {
    const unsigned short* g0 = gK + (size_t)(jt * 64 + w * 16 + srow) * 2048 + sblkg * 8;
    unsigned short* l0 = &Kbuf[(w * 16) * 64];
#pragma unroll
    for (int i = 0; i < 2; ++i) GLOAD16(g0 + (size_t)i * 8 * 2048, &l0[i * 512]);
  } else {
    const unsigned short* g0 = gV + (size_t)((w - 4) * 16 + srow) * 2048 + jt * 64 + sblkg * 8;
    unsigned short* l0 = &Vbuf[((w - 4) * 16) * 64];
#pragma unroll
    for (int i = 0; i < 2; ++i) GLOAD16(g0 + (size_t)i * 8 * 2048, &l0[i * 512]);
  }
}

// ---------------------------------------------------------------------------
// Split-K bf16 MFMA flash attention (fixed-max softmax => partials additive).
// Grid (S/256, H, B*2), 512 thr (8 waves). z = b*2 + half; half processes
// j in [half*1024, half*1024+1024). Writes UNNORMALIZED O^T partial (bf16)
// + per-row l partial (fp32). Wave w owns q-rows q0+32w..+31.
// ---------------------------------------------------------------------------
__global__ __launch_bounds__(512) void attn5(
    const unsigned short* __restrict__ qk, const unsigned short* __restrict__ vt,
    unsigned short* __restrict__ ph0, unsigned short* __restrict__ ph1,
    float* __restrict__ lsum) {
  __shared__ __attribute__((aligned(16))) unsigned short Ks[2][64 * 64];  // 16 KB
  __shared__ __attribute__((aligned(16))) unsigned short Vs[2][64 * 64];  // 16 KB
  __shared__ __attribute__((aligned(16))) unsigned short Ps[8][32 * 64];  // 32 KB

  const int tid = threadIdx.x;
  const int w = tid >> 6, lane = tid & 63, quad = lane >> 4, c = lane & 15;
  const int h = blockIdx.y;
  const int b = blockIdx.z >> 1, half = blockIdx.z & 1;
  const int q0 = blockIdx.x * 256 + w * 32;
  const int tstart = half * 16;
  const int rk = c & 7;

  // persistent Q frags (B-operand): 2 mi-groups x 2 d-steps; q pre-scaled by CF
  short8_t qf[2][2];
  {
    const size_t rb = (size_t)b * SEQ + q0;
#pragma unroll
    for (int mi = 0; mi < 2; ++mi) {
      const size_t qr = (rb + mi * 16 + c) * 2048 + h * 64 + quad * 8;
      qf[mi][0] = *(const short8_t*)&qk[qr];
      qf[mi][1] = *(const short8_t*)&qk[qr + 32];
    }
  }
  __asm__ __volatile__("s_waitcnt vmcnt(0)" ::: "memory");  // clean vmcnt queue

  floatx4 O[2][4], Osum[2];
  const floatx4 z = {0.f, 0.f, 0.f, 0.f};
#pragma unroll
  for (int mi = 0; mi < 2; ++mi) {
    Osum[mi] = z;
#pragma unroll
    for (int dg = 0; dg < 4; ++dg) O[mi][dg] = z;
  }
  short8_t ones;
#pragma unroll
  for (int e = 0; e < 8; ++e) ones[e] = (short)0x3F80;  // bf16 1.0

  const int srow = lane >> 3;           // 0..7
  const int sblkg = (lane & 7) ^ srow;  // staging chunk swizzle
  const unsigned short* gK = qk + (size_t)b * SEQ * 2048 + 1024 + h * 64;
  const unsigned short* gV = vt + (size_t)(b * 16 + h) * 64 * 2048;
  unsigned short* myPs = Ps[w];

  stage_kv8(w, srow, sblkg, gK, gV, Ks[0], Vs[0], tstart);

  for (int t = 0; t < 16; ++t) {
    const int cur = t & 1;
    WGBAR();  // all waves done reading buf[cur^1] (tile t-1)
    stage_kv8(w, srow, sblkg, gK, gV, Ks[cur ^ 1], Vs[cur ^ 1], tstart + ((t + 1) & 15));
    __asm__ __volatile__("s_waitcnt vmcnt(2)" ::: "memory");  // own tile-t loads landed
    WGBAR();  // all waves' tile-t loads landed
    const unsigned short* Kc = Ks[cur];
    const unsigned short* Vc = Vs[cur];

    // S^T = K Q^T: lane = q, regs = j (consecutive within quad)
    floatx4 S[2][4];
#pragma unroll
    for (int mi = 0; mi < 2; ++mi)
#pragma unroll
      for (int jg = 0; jg < 4; ++jg) S[mi][jg] = z;
#pragma unroll
    for (int kd = 0; kd < 2; ++kd) {
      const int oct = ((4 * kd + quad) ^ rk) * 8;
#pragma unroll
      for (int jg = 0; jg < 4; ++jg) {
        short8_t kf = *(const short8_t*)&Kc[(jg * 16 + c) * 64 + oct];
#pragma unroll
        for (int mi = 0; mi < 2; ++mi)
          S[mi][jg] = __builtin_amdgcn_mfma_f32_16x16x32_bf16(kf, qf[mi][kd], S[mi][jg], 0, 0, 0);
      }
    }

    // P = exp2(S^T), truncate to bf16, pack consecutive-j pairs -> b32 LDS
#pragma unroll
    for (int mi = 0; mi < 2; ++mi) {
      const int qrow = (mi * 16 + c) * 64;
#pragma unroll
      for (int jg = 0; jg < 4; ++jg) {
        float p0 = __builtin_amdgcn_exp2f(S[mi][jg][0]);
        float p1 = __builtin_amdgcn_exp2f(S[mi][jg][1]);
        float p2 = __builtin_amdgcn_exp2f(S[mi][jg][2]);
        float p3 = __builtin_amdgcn_exp2f(S[mi][jg][3]);
        unsigned int pk01 = (__float_as_uint(p1) & 0xFFFF0000u) | (__float_as_uint(p0) >> 16);
        unsigned int pk23 = (__float_as_uint(p3) & 0xFFFF0000u) | (__float_as_uint(p2) >> 16);
        const int jp0 = 8 * jg + 2 * quad;
#pragma unroll
        for (int u = 0; u < 2; ++u) {
          const int jp = jp0 + u;
          const int off = ((jp >> 2) ^ rk) * 8 + (jp & 3) * 2;
          *(unsigned int*)&myPs[qrow + off] = u ? pk23 : pk01;
        }
      }
    }
    __asm__ __volatile__("s_waitcnt lgkmcnt(0)" ::: "memory");

    // PV: O^T += V^T P^T ; l += ones . P^T
#pragma unroll
    for (int kq = 0; kq < 2; ++kq) {
      const int oct = ((4 * kq + quad) ^ rk) * 8;
      short8_t pb[2];
#pragma unroll
      for (int mi = 0; mi < 2; ++mi) {
        pb[mi] = *(const short8_t*)&myPs[(mi * 16 + c) * 64 + oct];
        Osum[mi] = __builtin_amdgcn_mfma_f32_16x16x32_bf16(ones, pb[mi], Osum[mi], 0, 0, 0);
      }
#pragma unroll
      for (int dg = 0; dg < 4; ++dg) {
        short8_t vf = *(const short8_t*)&Vc[(dg * 16 + c) * 64 + oct];
#pragma unroll
        for (int mi = 0; mi < 2; ++mi)
          O[mi][dg] = __builtin_amdgcn_mfma_f32_16x16x32_bf16(vf, pb[mi], O[mi][dg], 0, 0, 0);
      }
    }
  }

  __asm__ __volatile__("s_waitcnt vmcnt(0)" ::: "memory");  // drain trailing DMA

  // epilogue: UNNORMALIZED partial O^T -> bf16 (lane=q, regs=consecutive d);
  // l partial -> fp32 (quad 0 lanes only; all quads hold identical Osum)
  unsigned short* ph = half ? ph1 : ph0;
#pragma unroll
  for (int mi = 0; mi < 2; ++mi) {
    const size_t row = (size_t)b * SEQ + q0 + mi * 16 + c;
#pragma unroll
    for (int dg = 0; dg < 4; ++dg) {
      ushort4_t ov = {f2bf(O[mi][dg][0]), f2bf(O[mi][dg][1]),
                      f2bf(O[mi][dg][2]), f2bf(O[mi][dg][3])};
      *(ushort4_t*)&ph[row * EMB + h * 64 + dg * 16 + quad * 4] = ov;
    }
    if (quad == 0)
      lsum[((size_t)(half * 2 + b) * 16 + h) * 2048 + q0 + mi * 16 + c] = Osum[mi][0];
  }
}

// ---------------------------------------------------------------------------
// Combine split-K halves: aob = (p0 + p1) / (l0 + l1), bf16.
// aob aliases p0's memory (in-place safe: read-then-write same index).
// ---------------------------------------------------------------------------
__global__ __launch_bounds__(256) void combine(
    const unsigned short* __restrict__ p0, const unsigned short* __restrict__ p1,
    const float* __restrict__ lsum, unsigned short* __restrict__ aob) {
  const int i = blockIdx.x * 256 + threadIdx.x;  // 4-elem groups
  const size_t base = (size_t)i * 4;
  const int e = (int)(base & (EMB - 1));
  const size_t row = base >> 10;  // b*SEQ + s
  const int b = (int)(row >> 11), s = (int)(row & 2047), h = e >> 6;
  const float l0 = lsum[((size_t)(0 + b) * 16 + h) * 2048 + s];
  const float l1 = lsum[((size_t)(2 + b) * 16 + h) * 2048 + s];
  const float inv = 1.0f / (l0 + l1);
  ushort4_t a = *(const ushort4_t*)&p0[base];
  ushort4_t d = *(const ushort4_t*)&p1[base];
  ushort4_t o;
#pragma unroll
  for (int k = 0; k < 4; ++k) o[k] = f2bf((bf2f(a[k]) + bf2f(d[k])) * inv);
  *(ushort4_t*)&aob[base] = o;
}

// ---------------------------------------------------------------------------
extern "C" void kernel_launch(void* const* d_in, const int* in_sizes, int n_in,
                              void* d_out, int out_size, void* d_ws, size_t ws_size,
                              hipStream_t stream) {
  const float* hs = (const float*)d_in[0];        // [B,S,E]
  const float* c_attn_w = (const float*)d_in[1];  // [E,3E]
  const float* c_attn_b = (const float*)d_in[2];  // [3E]
  const float* c_proj_w = (const float*)d_in[3];  // [E,E]
  const float* c_proj_b = (const float*)d_in[4];  // [E]
  float* out = (float*)d_out;                     // [B,S,E] fp32

  char* ws = (char*)d_ws;
  unsigned short* hsb = (unsigned short*)(ws + 0);         // 8.39 MB [B,S,E] bf16; reused as ph1
  unsigned short* qk  = (unsigned short*)(ws + 8388608);   // 16.8 MB [B,S,2048]
  unsigned short* vt  = (unsigned short*)(ws + 25165824);  // 8.39 MB [B,H,D,S]
  unsigned short* ph0 = (unsigned short*)(ws + 33554432);  // 8.39 MB partial 0 -> aob
  unsigned short* w1t = (unsigned short*)(ws + 41943040);  // 6.29 MB [3072,1024]
  unsigned short* w2t = (unsigned short*)(ws + 48234496);  // 2.10 MB [1024,1024]
  float*          lsum = (float*)(ws + 50331648);          // 1.05 MB [half,B,H,S]
  unsigned short* ph1 = hsb;  // hsb dead after gemm0; attn writes ph1 there

  // 1) hidden_states -> bf16
  conv_bf<<<4096, 256, 0, stream>>>(hs, hsb, (2 * SEQ * EMB) / 4);
  // 2) transpose+convert weights
  tconv<<<dim3(48, 16), 256, 0, stream>>>(c_attn_w, w1t, 3 * EMB, EMB);
  tconv<<<dim3(16, 16), 256, 0, stream>>>(c_proj_w, w2t, EMB, EMB);
  // 3) QKV GEMM: q/k cols (transposed-C epilogue) + v cols (vt layout)
  gemm_bf<0, 128><<<dim3(16, 32), 256, 0, stream>>>(hsb, w1t, c_attn_b, nullptr, qk, nullptr, 0);
  gemm_bf<1, 128><<<dim3(8, 32), 256, 0, stream>>>(hsb, w1t, c_attn_b, nullptr, nullptr, vt, 2048);
  // 4) split-K attention -> unnormalized bf16 partials + l
  attn5<<<dim3(8, 16, 4), 512, 0, stream>>>(qk, vt, ph0, ph1, lsum);
  // 5) combine halves -> aob (in ph0's memory)
  combine<<<4096, 256, 0, stream>>>(ph0, ph1, lsum, ph0);
  // 6) output projection -> fp32 out (transposed-C epilogue, float4 stores)
  gemm_bf<2, 64><<<dim3(16, 32), 256, 0, stream>>>(ph0, w2t, c_proj_b, out, nullptr, nullptr, 0);
}

// Round 7
// 193.443 us; speedup vs baseline: 1.0800x; 1.0800x over previous
//
#include <hip/hip_runtime.h>

// B=2, S=2048, E=1024, H=16, D=64
#define SEQ 2048
#define EMB 1024
#define KDIM 1024
#define CF 0.180336880111113f  // (1/sqrt(64)) * log2(e), folded into Q

typedef __attribute__((ext_vector_type(8))) short short8_t;
typedef __attribute__((ext_vector_type(4))) float floatx4;
typedef __attribute__((ext_vector_type(4))) unsigned short ushort4_t;

#define GLOAD16(gp, lp)                                                        \
  __builtin_amdgcn_global_load_lds(                                            \
      (const __attribute__((address_space(1))) void*)(gp),                     \
      (__attribute__((address_space(3))) void*)(lp), 16, 0, 0)

#define WGBAR()                                   \
  do {                                            \
    __asm__ __volatile__("" ::: "memory");        \
    __builtin_amdgcn_s_barrier();                 \
    __asm__ __volatile__("" ::: "memory");        \
  } while (0)

static __device__ __forceinline__ unsigned short f2bf(float x) {
  unsigned int u = __float_as_uint(x);
  return (unsigned short)((u + 0x7fffu + ((u >> 16) & 1u)) >> 16);
}

// ---------------------------------------------------------------------------
// Fused prepass: blockIdx 0..4095   -> hs fp32 -> bf16
//                4096..4863         -> c_attn_w [1024,3072] -> w1t [3072,1024]
//                4864..5119         -> c_proj_w [1024,1024] -> w2t [1024,1024]
// ---------------------------------------------------------------------------
static __device__ __forceinline__ void tconv_tile(
    const float* __restrict__ W, unsigned short* __restrict__ T, int N, int K,
    int n0, int k0, int tid) {
  __shared__ float Tl[64][65];
  const int lx = tid & 15, ly = tid >> 4;
#pragma unroll
  for (int u = 0; u < 4; ++u) {
    int r = u * 16 + ly;
    float4 v = *(const float4*)&W[(size_t)(k0 + r) * N + n0 + lx * 4];
    Tl[r][lx * 4 + 0] = v.x;
    Tl[r][lx * 4 + 1] = v.y;
    Tl[r][lx * 4 + 2] = v.z;
    Tl[r][lx * 4 + 3] = v.w;
  }
  __syncthreads();
#pragma unroll
  for (int u = 0; u < 4; ++u) {
    int n = u * 16 + ly;
    ushort4_t h;
#pragma unroll
    for (int v = 0; v < 4; ++v) h[v] = f2bf(Tl[lx * 4 + v][n]);
    *(ushort4_t*)&T[(size_t)(n0 + n) * K + k0 + lx * 4] = h;
  }
}

__global__ __launch_bounds__(256) void prep(
    const float* __restrict__ hs, const float* __restrict__ caw,
    const float* __restrict__ cpw, unsigned short* __restrict__ hsb,
    unsigned short* __restrict__ w1t, unsigned short* __restrict__ w2t) {
  const int bid = blockIdx.x, tid = threadIdx.x;
  if (bid < 4096) {
    const int i = bid * 256 + tid;
    float4 v = *(const float4*)&hs[(size_t)i * 4];
    ushort4_t h = {f2bf(v.x), f2bf(v.y), f2bf(v.z), f2bf(v.w)};
    *(ushort4_t*)&hsb[(size_t)i * 4] = h;
  } else if (bid < 4864) {
    const int idx = bid - 4096;
    tconv_tile(caw, w1t, 3 * EMB, EMB, (idx % 48) * 64, (idx / 48) * 64, tid);
  } else {
    const int idx = bid - 4864;
    tconv_tile(cpw, w2t, EMB, EMB, (idx % 16) * 64, (idx / 16) * 64, tid);
  }
}

// ---------------------------------------------------------------------------
// Plain bf16 MFMA GEMM, BK=64, transposed-C accumulators (regs = 4
// consecutive output cols):  C = A @ Bt^T + bias.  Tile 128 x BN.
//   A: [M,1024] bf16 row-major;  Bt: [N,1024] bf16 (W transposed)
// MODE 0 (BN=128, grid 24x32): cols<2048 -> qk bf16 [B,S,2048] (q scaled CF,
//   ushort4 stores); cols>=2048 -> vt bf16 [B,H,D,S] (4 row-strided stores).
// MODE 2 (BN=64, grid 16x32): fp32 out [M,1024], float4 stores.
// ---------------------------------------------------------------------------
template <int MODE, int BN>
__global__ __launch_bounds__(256) void gemm_bf(
    const unsigned short* __restrict__ Ag, const unsigned short* __restrict__ Bg,
    const float* __restrict__ bias, float* __restrict__ outF,
    unsigned short* __restrict__ qk, unsigned short* __restrict__ vt) {
  __shared__ __attribute__((aligned(16))) unsigned short Ah[128 * 64];
  __shared__ __attribute__((aligned(16))) unsigned short Bh[BN * 64];
  const int NJ = BN / 32;  // j-frag groups per wave

  const int tid = threadIdx.x;
  const int w = tid >> 6, lane = tid & 63;
  const int quad = lane >> 4, c = lane & 15;
  const int bm = blockIdx.y * 128, bn = blockIdx.x * BN;
  const int wm = (w >> 1) * 64, wn = (w & 1) * (BN / 2);

  // staging: waves 0,1 -> A halves; waves 2,3 -> B halves
  const unsigned short* gsrc = (w < 2) ? Ag : Bg;
  unsigned short* ldst = (w < 2) ? (Ah + (w & 1) * 64 * 64) : (Bh + (w & 1) * (BN / 2) * 64);
  const int rbase = (w < 2) ? (bm + (w & 1) * 64) : (bn + (w & 1) * (BN / 2));
  const int nloads = (w < 2) ? 8 : (BN / 16);
  const int srow = lane >> 3;          // 0..7
  const int sblk = (lane & 7) ^ srow;  // XOR chunk swizzle (8x16B chunks/row)
  const char* gp0 = (const char*)(gsrc + (size_t)(rbase + srow) * KDIM) + sblk * 16;

  floatx4 acc[4][NJ];
  const floatx4 z = {0.f, 0.f, 0.f, 0.f};
#pragma unroll
  for (int i = 0; i < 4; ++i)
#pragma unroll
    for (int j = 0; j < NJ; ++j) acc[i][j] = z;

  const int rk = c & 7;  // read-side swizzle key (row&7 == c&7)

  for (int k0 = 0; k0 < KDIM; k0 += 64) {
    __syncthreads();
    const char* gp = gp0 + k0 * 2;
    for (int i = 0; i < nloads; ++i) GLOAD16(gp + (size_t)i * 8 * (KDIM * 2), &ldst[i * 512]);
    __syncthreads();

#pragma unroll
    for (int kq = 0; kq < 2; ++kq) {
      const int oct = ((4 * kq + quad) ^ rk) * 8;
      short8_t a[4], b[NJ];
#pragma unroll
      for (int i = 0; i < 4; ++i)
        a[i] = *(const short8_t*)&Ah[(wm + 16 * i + c) * 64 + oct];
#pragma unroll
      for (int j = 0; j < NJ; ++j)
        b[j] = *(const short8_t*)&Bh[(wn + 16 * j + c) * 64 + oct];
      // transposed: lane = A-row (m), regs = 4 consecutive B-rows (n)
#pragma unroll
      for (int i = 0; i < 4; ++i)
#pragma unroll
        for (int j = 0; j < NJ; ++j)
          acc[i][j] = __builtin_amdgcn_mfma_f32_16x16x32_bf16(b[j], a[i], acc[i][j], 0, 0, 0);
    }
  }

#pragma unroll
  for (int i = 0; i < 4; ++i) {
    const int row = bm + wm + 16 * i + c;
#pragma unroll
    for (int j = 0; j < NJ; ++j) {
      const int col0 = bn + wn + 16 * j + quad * 4;
      floatx4 v = acc[i][j] + *(const floatx4*)&bias[col0];
      if (MODE == 0) {
        if (col0 < 1024) v = v * CF;
        if (col0 < 2048) {
          ushort4_t pk = {f2bf(v[0]), f2bf(v[1]), f2bf(v[2]), f2bf(v[3])};
          *(ushort4_t*)&qk[(size_t)row * 2048 + col0] = pk;
        } else {
          const int c2 = col0 - 2048, hh = c2 >> 6, d0 = c2 & 63;
          const int bb = row >> 11, s = row & 2047;
          unsigned short* vb = &vt[((size_t)(bb * 16 + hh) * 64 + d0) * 2048 + s];
          vb[0 * 2048] = f2bf(v[0]);
          vb[1 * 2048] = f2bf(v[1]);
          vb[2 * 2048] = f2bf(v[2]);
          vb[3 * 2048] = f2bf(v[3]);
        }
      } else {
        *(floatx4*)&outF[(size_t)row * 1024 + col0] = v;
      }
    }
  }
}

// ---------------------------------------------------------------------------
// K/V staging: waves 0,1 stage K rows w*32..+31; waves 2,3 stage V^T rows.
// 4 GLOAD16 per wave per tile.
// ---------------------------------------------------------------------------
static __device__ __forceinline__ void stage_kv(
    int w, int srow, int sblkg, const unsigned short* __restrict__ gK,
    const unsigned short* __restrict__ gV, unsigned short* Kbuf,
    unsigned short* Vbuf, int jt) {
  if (w < 2) {
    const unsigned short* g0 = gK + (size_t)(jt * 64 + w * 32 + srow) * 2048 + sblkg * 8;
    unsigned short* l0 = &Kbuf[(w * 32) * 64];
#pragma unroll
    for (int i = 0; i < 4; ++i) GLOAD16(g0 + (size_t)i * 8 * 2048, &l0[i * 512]);
  } else {
    const unsigned short* g0 = gV + (size_t)((w - 2) * 32 + srow) * 2048 + jt * 64 + sblkg * 8;
    unsigned short* l0 = &Vbuf[((w - 2) * 32) * 64];
#pragma unroll
    for (int i = 0; i < 4; ++i) GLOAD16(g0 + (size_t)i * 8 * 2048, &l0[i * 512]);
  }
}

// ---------------------------------------------------------------------------
// bf16 MFMA flash attention, fixed-max softmax, S^T formulation,
// TRIPLE-buffered K/V with ONE barrier per tile (prefetch depth 2):
//   iter t: vmcnt(4) [own stage-t landed] -> s_barrier [all stage-t landed,
//   all compute t-1 done] -> stage t+2 [overwrites tile t-1's buffer: its
//   readers finished before this barrier] -> compute t.
// Grid (S/128, H, B), 256 thr. Wave w owns q-rows q0+32w..+31.
// ---------------------------------------------------------------------------
__global__ __launch_bounds__(256) void attn6(
    const unsigned short* __restrict__ qk, const unsigned short* __restrict__ vt,
    unsigned short* __restrict__ ao) {
  __shared__ __attribute__((aligned(16))) unsigned short Ks[3][64 * 64];  // 24 KB
  __shared__ __attribute__((aligned(16))) unsigned short Vs[3][64 * 64];  // 24 KB
  __shared__ __attribute__((aligned(16))) unsigned short Ps[4][32 * 64];  // 16 KB

  const int tid = threadIdx.x;
  const int w = tid >> 6, lane = tid & 63, quad = lane >> 4, c = lane & 15;
  const int q0 = blockIdx.x * 128, h = blockIdx.y, b = blockIdx.z;
  const int rk = c & 7;

  // persistent Q frags (B-operand): 2 mi-groups x 2 d-steps; q pre-scaled CF
  short8_t qf[2][2];
  {
    const size_t rb = (size_t)b * SEQ + q0 + w * 32;
#pragma unroll
    for (int mi = 0; mi < 2; ++mi) {
      const size_t qr = (rb + mi * 16 + c) * 2048 + h * 64 + quad * 8;
      qf[mi][0] = *(const short8_t*)&qk[qr];
      qf[mi][1] = *(const short8_t*)&qk[qr + 32];
    }
  }
  __asm__ __volatile__("s_waitcnt vmcnt(0)" ::: "memory");  // clean vmcnt queue

  floatx4 O[2][4], Osum[2];
  const floatx4 z = {0.f, 0.f, 0.f, 0.f};
#pragma unroll
  for (int mi = 0; mi < 2; ++mi) {
    Osum[mi] = z;
#pragma unroll
    for (int dg = 0; dg < 4; ++dg) O[mi][dg] = z;
  }
  short8_t ones;
#pragma unroll
  for (int e = 0; e < 8; ++e) ones[e] = (short)0x3F80;  // bf16 1.0

  const int srow = lane >> 3;           // 0..7
  const int sblkg = (lane & 7) ^ srow;  // staging chunk swizzle
  const unsigned short* gK = qk + (size_t)b * SEQ * 2048 + 1024 + h * 64;
  const unsigned short* gV = vt + (size_t)(b * 16 + h) * 64 * 2048;
  unsigned short* myPs = Ps[w];

  stage_kv(w, srow, sblkg, gK, gV, Ks[0], Vs[0], 0);
  stage_kv(w, srow, sblkg, gK, gV, Ks[1], Vs[1], 1);

  for (int t = 0; t < 32; ++t) {
    // own stage-t loads landed (leaves the 4 stage-(t+1) loads in flight)
    __asm__ __volatile__("s_waitcnt vmcnt(4)" ::: "memory");
    WGBAR();  // all waves: stage-t landed AND compute t-1 finished
    stage_kv(w, srow, sblkg, gK, gV, Ks[(t + 2) % 3], Vs[(t + 2) % 3], (t + 2) & 31);
    const unsigned short* Kc = Ks[t % 3];
    const unsigned short* Vc = Vs[t % 3];

    // S^T = K Q^T: lane = q, regs = j (consecutive within quad)
    floatx4 S[2][4];
#pragma unroll
    for (int mi = 0; mi < 2; ++mi)
#pragma unroll
      for (int jg = 0; jg < 4; ++jg) S[mi][jg] = z;
#pragma unroll
    for (int kd = 0; kd < 2; ++kd) {
      const int oct = ((4 * kd + quad) ^ rk) * 8;
#pragma unroll
      for (int jg = 0; jg < 4; ++jg) {
        short8_t kf = *(const short8_t*)&Kc[(jg * 16 + c) * 64 + oct];
#pragma unroll
        for (int mi = 0; mi < 2; ++mi)
          S[mi][jg] = __builtin_amdgcn_mfma_f32_16x16x32_bf16(kf, qf[mi][kd], S[mi][jg], 0, 0, 0);
      }
    }

    // P = exp2(S^T), truncate to bf16, pack consecutive-j pairs -> b32 LDS
#pragma unroll
    for (int mi = 0; mi < 2; ++mi) {
      const int qrow = (mi * 16 + c) * 64;
#pragma unroll
      for (int jg = 0; jg < 4; ++jg) {
        float p0 = __builtin_amdgcn_exp2f(S[mi][jg][0]);
        float p1 = __builtin_amdgcn_exp2f(S[mi][jg][1]);
        float p2 = __builtin_amdgcn_exp2f(S[mi][jg][2]);
        float p3 = __builtin_amdgcn_exp2f(S[mi][jg][3]);
        unsigned int pk01 = (__float_as_uint(p1) & 0xFFFF0000u) | (__float_as_uint(p0) >> 16);
        unsigned int pk23 = (__float_as_uint(p3) & 0xFFFF0000u) | (__float_as_uint(p2) >> 16);
        const int jp0 = 8 * jg + 2 * quad;
#pragma unroll
        for (int u = 0; u < 2; ++u) {
          const int jp = jp0 + u;
          const int off = ((jp >> 2) ^ rk) * 8 + (jp & 3) * 2;
          *(unsigned int*)&myPs[qrow + off] = u ? pk23 : pk01;
        }
      }
    }
    __asm__ __volatile__("s_waitcnt lgkmcnt(0)" ::: "memory");

    // PV: O^T += V^T P^T ; l += ones . P^T
#pragma unroll
    for (int kq = 0; kq < 2; ++kq) {
      const int oct = ((4 * kq + quad) ^ rk) * 8;
      short8_t pb[2];
#pragma unroll
      for (int mi = 0; mi < 2; ++mi) {
        pb[mi] = *(const short8_t*)&myPs[(mi * 16 + c) * 64 + oct];
        Osum[mi] = __builtin_amdgcn_mfma_f32_16x16x32_bf16(ones, pb[mi], Osum[mi], 0, 0, 0);
      }
#pragma unroll
      for (int dg = 0; dg < 4; ++dg) {
        short8_t vf = *(const short8_t*)&Vc[(dg * 16 + c) * 64 + oct];
#pragma unroll
        for (int mi = 0; mi < 2; ++mi)
          O[mi][dg] = __builtin_amdgcn_mfma_f32_16x16x32_bf16(vf, pb[mi], O[mi][dg], 0, 0, 0);
      }
    }
  }

  __asm__ __volatile__("s_waitcnt vmcnt(0)" ::: "memory");  // drain trailing DMA

  // epilogue: lane = q, regs = consecutive d -> packed ushort4 stores
#pragma unroll
  for (int mi = 0; mi < 2; ++mi) {
    const float inv = 1.0f / Osum[mi][0];
    const size_t row = (size_t)b * SEQ + q0 + w * 32 + mi * 16 + c;
#pragma unroll
    for (int dg = 0; dg < 4; ++dg) {
      ushort4_t ov = {f2bf(O[mi][dg][0] * inv), f2bf(O[mi][dg][1] * inv),
                      f2bf(O[mi][dg][2] * inv), f2bf(O[mi][dg][3] * inv)};
      *(ushort4_t*)&ao[row * EMB + h * 64 + dg * 16 + quad * 4] = ov;
    }
  }
}

// ---------------------------------------------------------------------------
extern "C" void kernel_launch(void* const* d_in, const int* in_sizes, int n_in,
                              void* d_out, int out_size, void* d_ws, size_t ws_size,
                              hipStream_t stream) {
  const float* hs = (const float*)d_in[0];        // [B,S,E]
  const float* c_attn_w = (const float*)d_in[1];  // [E,3E]
  const float* c_attn_b = (const float*)d_in[2];  // [3E]
  const float* c_proj_w = (const float*)d_in[3];  // [E,E]
  const float* c_proj_b = (const float*)d_in[4];  // [E]
  float* out = (float*)d_out;                     // [B,S,E] fp32

  char* ws = (char*)d_ws;
  unsigned short* hsb = (unsigned short*)(ws + 0);         // 8.39 MB [B,S,E] bf16
  unsigned short* qk  = (unsigned short*)(ws + 8388608);   // 16.8 MB [B,S,2048]
  unsigned short* vt  = (unsigned short*)(ws + 25165824);  // 8.39 MB [B,H,D,S]
  unsigned short* aob = (unsigned short*)(ws + 33554432);  // 8.39 MB [B,S,E] bf16
  unsigned short* w1t = (unsigned short*)(ws + 41943040);  // 6.29 MB [3072,1024]
  unsigned short* w2t = (unsigned short*)(ws + 48234496);  // 2.10 MB [1024,1024]

  // 1) fused prepass: hs->bf16, transpose+convert both weight matrices
  prep<<<5120, 256, 0, stream>>>(hs, c_attn_w, c_proj_w, hsb, w1t, w2t);
  // 2) QKV GEMM -> qk (q pre-scaled by CF) + vt (V transposed)
  gemm_bf<0, 128><<<dim3(24, 32), 256, 0, stream>>>(hsb, w1t, c_attn_b, nullptr, qk, vt);
  // 3) attention -> aob bf16
  attn6<<<dim3(16, 16, 2), 256, 0, stream>>>(qk, vt, aob);
  // 4) output projection -> fp32 out (float4 stores)
  gemm_bf<2, 64><<<dim3(16, 32), 256, 0, stream>>>(aob, w2t, c_proj_b, out, nullptr, nullptr);
}